// Round 5
// baseline (4354.087 us; speedup 1.0000x reference)
//
#include <hip/hip_runtime.h>
#include <cstdint>

// Problem constants
static constexpr int BATCH  = 32;
static constexpr int TLEN   = 2048;
static constexpr int DIN    = 256;    // input dim
static constexpr int HDIM   = 512;    // hidden dim
static constexpr int G4     = 2048;   // 4*HDIM (gate cols, order i,f,g,o)
static constexpr int NSLICE = 8;      // blocks per batch
static constexpr int HCB    = 64;     // h-cols per block
static constexpr int CPB    = 256;    // gate-cols per block (4 * HCB)
static constexpr int NTHR   = 512;    // 8 waves
static constexpr int NWAVE  = 8;
static constexpr int KL     = 96;     // k-values per wave
static constexpr int KL2    = 48;     // packed f16x2 (u32) per wave
static constexpr int NBLK   = BATCH * NSLICE;  // 256 blocks = 1/CU
static constexpr int SC0_SPIN_MAX = 1024;      // bounded fast-poll (~50us)

typedef _Float16 h2v __attribute__((ext_vector_type(2)));

__device__ __forceinline__ uint32_t pack_f16x2(float a, float b) {
    h2v v;
    v[0] = (_Float16)a;   // scalar f32->f16 converts RTN
    v[1] = (_Float16)b;
    return __builtin_bit_cast(uint32_t, v);
}

__device__ __forceinline__ float dot2f(uint32_t w, uint32_t u, float acc) {
#if __has_builtin(__builtin_amdgcn_fdot2)
    return __builtin_amdgcn_fdot2(__builtin_bit_cast(h2v, w),
                                  __builtin_bit_cast(h2v, u), acc, false);
#else
    h2v a = __builtin_bit_cast(h2v, w);
    h2v b = __builtin_bit_cast(h2v, u);
    return acc + (float)a[0] * (float)b[0] + (float)a[1] * (float)b[1];
#endif
}

__device__ __forceinline__ float sigmoidf_(float x) {
    return 1.0f / (1.0f + __expf(-x));
}
// tanh via exp; handles +-inf saturation correctly
__device__ __forceinline__ float tanhf_(float x) {
    return 1.0f - 2.0f / (1.0f + __expf(2.0f * x));
}

// sc0 load: bypass L1, read the XCD-local L2 (~200cy RT vs ~600-900cy
// fabric/MALL). Used ONLY as a bounded fast-poll; correctness never
// depends on its coherence (sticky fallback to agent-scope polls below).
__device__ __forceinline__ uint64_t load_l2_u64(const uint64_t* p) {
    uint64_t r;
    // "=&v": early-clobber so the dest pair can never alias the address
    // pair (the poll loop re-issues with the same address register).
    asm volatile("global_load_dwordx2 %0, %1, off sc0\n\t"
                 "s_waitcnt vmcnt(0)"
                 : "=&v"(r) : "v"(p) : "memory");
    return r;
}

// XCC (XCD) id via the portable builtin (numeric hwreg encoding: id 20 =
// XCC_ID, offset 0, width 32). Symbolic `hwreg(HW_REG_XCC_ID)` inline asm
// is an assembler-parse risk.
__device__ __forceinline__ uint32_t xcc_id() {
    return __builtin_amdgcn_s_getreg(20 | ((32 - 1) << 11)) & 0xFu;
}

__device__ __forceinline__ bool tag_ok(uint64_t v, uint32_t tag) {
    return (((uint32_t)(v >> 16) & 0xFFFFu) == tag) &&
           ((uint32_t)(v >> 48) == tag);
}

// Persistent LSTM: one launch runs all 2048 timesteps.
// grid = 32 batches x 8 slices, block = 512 threads, 1 block/CU.
//
// R2 (tagged words, VERIFIED 3903us): each h element is ONE u32
// (tag<<16 | f16); writers publish with relaxed AGENT atomics (sc0+sc1
// write-through to the MALL coherence point), readers poll the data words
// with agent loads. Proven live and correct.
// R5 (this round): READER-side only change. R3 used sc0 for BOTH sides;
// two empty-timing failures followed by broker-level container death are
// the signature of a wedged GPU -> treat "sc0 store leaves the line
// invisible to sc0 polls" as possible, i.e. R3 could hang. Now:
//  - writer: UNCHANGED proven agent store (write-through; same-XCD L2 is
//    updated/invalidated en route, MALL always updated).
//  - reader: if the one-time handshake proves all 8 slices of this batch
//    share one XCD (XCC_ID match), poll via sc0 L2 loads -- BOUNDED to
//    SC0_SPIN_MAX spins, then sticky per-lane fallback to the proven
//    agent poll. Every spin loop terminates under ANY cache model; the
//    only unbounded waits are the agent polls R2 already proved live.
// Expected: detect latency drops from fabric RT (~600-900cy) to L2 RT
// (~200cy) when the placement heuristic holds; zero hang risk otherwise.
//
// Race-freedom sketch (2-deep h parity buffer + gp parity):
//  - tag T lives in parity T&1; word tag T overwritten by T+2 only after
//    the owner slice finished step T+1, which required tag-(T+1) words from
//    ALL slices, which required every block's UPDATE(T), which is after
//    every block's barrier(T), which is after all polls for tag T passed.
//  - any wave's iteration-(t+2) write of gp[t&1] is program-ordered after
//    barrier(t+1), which requires wave 0's arrival, which follows
//    UPDATE(t)'s gp[t&1] reads.
__global__ __launch_bounds__(NTHR, 2) void lstm_persist(
    const float* __restrict__ x, const int* __restrict__ lens,
    const float* __restrict__ Wi, const float* __restrict__ Wh,
    const float* __restrict__ bias, float* __restrict__ out,
    uint32_t* __restrict__ hT,    // [2][BATCH][HDIM] u32 tagged f16
    uint32_t* __restrict__ hand)  // [BATCH][NSLICE] u32 handshake
{
    // Block -> (batch, slice); all 8 slices of a batch share bid&7, i.e.
    // one XCD under round-robin dispatch (verified at runtime below).
    const int bid = blockIdx.x;
    const int xcd = bid & 7;
    const int t8  = bid >> 3;          // 0..31
    const int b   = xcd * 4 + (t8 & 3);
    const int s   = t8 >> 2;           // slice 0..7

    const int tid = threadIdx.x;
    const int w   = tid >> 6;          // wave 0..7 -> k-chunk [96w, 96w+96)
    const int l   = tid & 63;          // lane -> gate-cols {4l..4l+3}

    __shared__ __align__(16) uint32_t u_lds[NWAVE][KL2];  // per-wave chunk, f16x2
    __shared__ float gp[2][NWAVE][CPB];                   // parity-dbuf partials

    // ---- one-time: weight slice -> registers, packed f16x2 --------------
    // wgt[q][m] covers gate-col (4l+q), k = {96w+2m, 96w+2m+1};
    // k<256 indexes Wi rows, k>=256 indexes Wh rows (fused operand order).
    uint32_t wgt[4][KL2];
    #pragma unroll
    for (int q = 0; q < 4; ++q) {
        const int c    = 4 * l + q;                       // local gate-col
        const int gcol = (c >> 6) * HDIM + s * HCB + (c & 63);
        #pragma unroll
        for (int m = 0; m < KL2; ++m) {
            const int k0 = KL * w + 2 * m;
            const int k1 = k0 + 1;
            const float f0 = (k0 < DIN) ? Wi[(size_t)k0 * G4 + gcol]
                                        : Wh[(size_t)(k0 - DIN) * G4 + gcol];
            const float f1 = (k1 < DIN) ? Wi[(size_t)k1 * G4 + gcol]
                                        : Wh[(size_t)(k1 - DIN) * G4 + gcol];
            wgt[q][m] = pack_f16x2(f0, f1);
        }
    }

    // ---- one-time: XCD co-residency handshake ---------------------------
    // Values are written once (0 -> 0x100|xcc, monotonic), so every block
    // reads the same 8 final values -> 'fast' is batch-uniform.
    const uint32_t xcc = xcc_id();
    if (tid == 0)
        __hip_atomic_store(&hand[b * NSLICE + s], 0x100u | xcc,
                           __ATOMIC_RELAXED, __HIP_MEMORY_SCOPE_AGENT);
    uint32_t e = 0x100u;   // neutral for lanes >= NSLICE
    for (;;) {
        if (l < NSLICE)
            e = __hip_atomic_load(&hand[b * NSLICE + l], __ATOMIC_RELAXED,
                                  __HIP_MEMORY_SCOPE_AGENT);
        if (__all(e >= 0x100u)) break;
    }
    const uint32_t e0 = __shfl(e, 0);
    bool use_sc0 = __all((l < NSLICE) ? (e == e0) : true);

    // update-thread persistent state (wave 0, lane j owns h-col s*64+j)
    float c_st = 0.f, lc_st = 0.f, lh_st = 0.f;
    float b_i = 0.f, b_f = 0.f, b_g = 0.f, b_o = 0.f;
    if (tid < HCB) {
        const int col = s * HCB + tid;
        b_i = bias[col];
        b_f = bias[HDIM + col];
        b_g = bias[2 * HDIM + col];
        b_o = bias[3 * HDIM + col];
    }
    const int len_b = lens[b];

    const float* xb = x + (size_t)b * TLEN * DIN;
    float* ys = out + 2 * BATCH * HDIM;   // out = [lc | lh | ys]

    // staging role for this lane: pair p=l of wave w's chunk (l<48 only)
    const int  k0     = KL * w + 2 * l;          // first k of this lane's pair
    const bool is_stg = (l < KL2);
    const bool is_x   = is_stg && (k0 < DIN);    // x pair: normal cached load
    const bool is_h   = is_stg && (k0 >= DIN);   // h pair: tagged-word poll

    // x prefetch one step ahead: keeps wave 0's HBM latency off the
    // publish->poll critical path (it computes x-dot right after update).
    float2 xx_cur = make_float2(0.f, 0.f);
    if (is_x) xx_cur = *(const float2*)(xb + k0);           // t = 0

    for (int t = 0; t < TLEN; ++t) {
        // ---- stage own chunk ------------------------------------------
        if (is_x) {
            u_lds[w][l] = pack_f16x2(xx_cur.x, xx_cur.y);
        } else if (is_h) {
            // poll both tagged words of the pair with one u64 load;
            // tag==t means h_t payload is valid (parity t&1 holds tag t).
            // Each u32 is self-validating, so u64 tearing is harmless.
            const uint64_t* src = (const uint64_t*)
                (hT + (((size_t)(t & 1) * BATCH + b) * HDIM + (k0 - DIN)));
            const uint32_t tag = (uint32_t)t;
            uint64_t v = 0;
            bool got = false;
            if (use_sc0) {
                // bounded fast poll through the XCD-local L2
                for (int spin = 0; spin < SC0_SPIN_MAX; ++spin) {
                    v = load_l2_u64(src);
                    if (tag_ok(v, tag)) { got = true; break; }
                }
                if (!got) use_sc0 = false;   // sticky: model wrong, go slow
            }
            if (!got) {
                // proven-live agent-scope poll (R2 path)
                for (;;) {
                    v = __hip_atomic_load(src, __ATOMIC_RELAXED,
                                          __HIP_MEMORY_SCOPE_AGENT);
                    if (tag_ok(v, tag)) break;
                }
            }
            // pack the two f16 payloads: bits[15:0] and bits[47:32]
            u_lds[w][l] = (uint32_t)(v & 0xFFFFu) |
                          (uint32_t)((v >> 16) & 0xFFFF0000u);
        }
        // issue next step's x load now; consumed next iteration
        if (is_x && (t + 1 < TLEN))
            xx_cur = *(const float2*)(xb + (size_t)(t + 1) * DIN + k0);

        // ---- dot phase: 4 gate-cols per lane, wave's 96-k chunk ---------
        float a0 = 0.f, a1 = 0.f, a2 = 0.f, a3 = 0.f;
        const uint4* uv = (const uint4*)&u_lds[w][0];
        #pragma unroll
        for (int m4 = 0; m4 < KL2 / 4; ++m4) {
            const uint4 uu = uv[m4];   // broadcast ds_read_b128
            a0 = dot2f(wgt[0][4 * m4 + 0], uu.x, a0);
            a0 = dot2f(wgt[0][4 * m4 + 1], uu.y, a0);
            a0 = dot2f(wgt[0][4 * m4 + 2], uu.z, a0);
            a0 = dot2f(wgt[0][4 * m4 + 3], uu.w, a0);
            a1 = dot2f(wgt[1][4 * m4 + 0], uu.x, a1);
            a1 = dot2f(wgt[1][4 * m4 + 1], uu.y, a1);
            a1 = dot2f(wgt[1][4 * m4 + 2], uu.z, a1);
            a1 = dot2f(wgt[1][4 * m4 + 3], uu.w, a1);
            a2 = dot2f(wgt[2][4 * m4 + 0], uu.x, a2);
            a2 = dot2f(wgt[2][4 * m4 + 1], uu.y, a2);
            a2 = dot2f(wgt[2][4 * m4 + 2], uu.z, a2);
            a2 = dot2f(wgt[2][4 * m4 + 3], uu.w, a2);
            a3 = dot2f(wgt[3][4 * m4 + 0], uu.x, a3);
            a3 = dot2f(wgt[3][4 * m4 + 1], uu.y, a3);
            a3 = dot2f(wgt[3][4 * m4 + 2], uu.z, a3);
            a3 = dot2f(wgt[3][4 * m4 + 3], uu.w, a3);
        }
        float4 av;
        av.x = a0; av.y = a1; av.z = a2; av.w = a3;
        *(float4*)&gp[t & 1][w][4 * l] = av;

        __syncthreads();   // the ONLY barrier per step

        // ---- update phase: wave 0 reduces 8 k-chunks, applies gates -----
        if (tid < HCB) {
            float si = b_i, sf = b_f, sg = b_g, so = b_o;
            #pragma unroll
            for (int ww = 0; ww < NWAVE; ++ww) {
                si += gp[t & 1][ww][tid];
                sf += gp[t & 1][ww][HCB + tid];
                sg += gp[t & 1][ww][2 * HCB + tid];
                so += gp[t & 1][ww][3 * HCB + tid];
            }
            const float ig = sigmoidf_(si);
            const float fg = sigmoidf_(sf);
            const float gg = tanhf_(sg);
            const float og = sigmoidf_(so);
            const float cn = fg * c_st + ig * gg;
            const float hn = og * tanhf_(cn);
            c_st = cn;
            if (t < len_b) { lc_st = cn; lh_st = hn; }
            // publish tagged h_{t+1} word to the other parity buffer with
            // the PROVEN agent-scope store (write-through: updates the
            // same-XCD L2 en route for sc0 pollers, and the MALL coherence
            // point for agent pollers). 32-bit store cannot tear; the tag
            // IS the flag, so no fence is needed.
            const _Float16 hf = (_Float16)hn;
            const uint32_t word = ((uint32_t)(t + 1) << 16) |
                                  (uint32_t)__builtin_bit_cast(uint16_t, hf);
            __hip_atomic_store(
                &hT[((size_t)((t + 1) & 1) * BATCH + b) * HDIM + s * HCB + tid],
                word, __ATOMIC_RELAXED, __HIP_MEMORY_SCOPE_AGENT);
            // ys output (fp32, unmasked like the reference scan)
            ys[((size_t)b * TLEN + t) * HDIM + s * HCB + tid] = hn;
        }
        // no second barrier: gp parity double-buffer covers the one-step
        // overlap, and the tagged-word dependency chain covers step t+2.
    }

    // latched carry outputs
    if (tid < HCB) {
        out[(size_t)b * HDIM + s * HCB + tid] = lc_st;
        out[BATCH * HDIM + (size_t)b * HDIM + s * HCB + tid] = lh_st;
    }
}

extern "C" void kernel_launch(void* const* d_in, const int* in_sizes, int n_in,
                              void* d_out, int out_size, void* d_ws, size_t ws_size,
                              hipStream_t stream)
{
    const float* x    = (const float*)d_in[0];   // [32,2048,256] f32
    const int*   lens = (const int*)d_in[1];     // [32] i32
    const float* Wi   = (const float*)d_in[2];   // [256,2048] f32
    const float* Wh   = (const float*)d_in[3];   // [512,2048] f32
    const float* bias = (const float*)d_in[4];   // [2048] f32
    float* out = (float*)d_out;                  // [lc(16384) | lh(16384) | ys]

    uint32_t* hT   = (uint32_t*)d_ws;            // [2][32][512] tagged u32
    uint32_t* hand = hT + 2 * BATCH * HDIM;      // [32][8] u32 handshake
    // Zero hT (both parities) + handshake. Parity 0 = (tag=0, h=0)
    // satisfies t=0 polls immediately (h_0 = 0); parity 1 = tag 0 matches
    // no polled tag (odd tags) so readers spin until written. hand=0 means
    // "XCD not yet published".
    const size_t init_bytes =
        ((size_t)2 * BATCH * HDIM + BATCH * NSLICE) * sizeof(uint32_t);
    hipMemsetAsync(d_ws, 0, init_bytes, stream);

    hipLaunchKernelGGL(lstm_persist, dim3(NBLK), dim3(NTHR), 0, stream,
                       x, lens, Wi, Wh, bias, out, hT, hand);
}

// Round 6
// 4009.305 us; speedup vs baseline: 1.0860x; 1.0860x over previous
//
#include <hip/hip_runtime.h>
#include <cstdint>

// Problem constants
static constexpr int BATCH  = 32;
static constexpr int TLEN   = 2048;
static constexpr int DIN    = 256;    // input dim
static constexpr int HDIM   = 512;    // hidden dim
static constexpr int G4     = 2048;   // 4*HDIM (gate cols, order i,f,g,o)
static constexpr int NSLICE = 8;      // blocks per batch
static constexpr int HCB    = 64;     // h-cols per block
static constexpr int CPB    = 256;    // gate-cols per block (4 * HCB)
static constexpr int NTHR   = 512;    // 8 waves
static constexpr int NWAVE  = 8;
static constexpr int KL     = 96;     // k-values per wave
static constexpr int KL2    = 48;     // packed f16x2 (u32) per wave
static constexpr int NBLK   = BATCH * NSLICE;  // 256 blocks = 1/CU

typedef _Float16 h2v __attribute__((ext_vector_type(2)));
typedef uint32_t u32x4 __attribute__((ext_vector_type(4)));

__device__ __forceinline__ uint32_t pack_f16x2(float a, float b) {
    h2v v;
    v[0] = (_Float16)a;   // scalar f32->f16 converts RTN
    v[1] = (_Float16)b;
    return __builtin_bit_cast(uint32_t, v);
}

__device__ __forceinline__ float dot2f(uint32_t w, uint32_t u, float acc) {
#if __has_builtin(__builtin_amdgcn_fdot2)
    return __builtin_amdgcn_fdot2(__builtin_bit_cast(h2v, w),
                                  __builtin_bit_cast(h2v, u), acc, false);
#else
    h2v a = __builtin_bit_cast(h2v, w);
    h2v b = __builtin_bit_cast(h2v, u);
    return acc + (float)a[0] * (float)b[0] + (float)a[1] * (float)b[1];
#endif
}

__device__ __forceinline__ float sigmoidf_(float x) {
    return 1.0f / (1.0f + __expf(-x));
}
// tanh via exp; handles +-inf saturation correctly
__device__ __forceinline__ float tanhf_(float x) {
    return 1.0f - 2.0f / (1.0f + __expf(2.0f * x));
}

// Agent-scope (device-coherent) 16B load: sc0+sc1 bypass the non-coherent
// L1/L2 to the MALL coherence point -- the exact path __hip_atomic_load
// (relaxed, agent) takes, but 4 words per request instead of 2. Halves the
// poll request rate. Value ordering is by dataflow through the asm output;
// the embedded vmcnt(0) guarantees r is valid on exit.
__device__ __forceinline__ u32x4 load_agent_u128(const uint32_t* p) {
    u32x4 r;
    asm volatile("global_load_dwordx4 %0, %1, off sc0 sc1\n\t"
                 "s_waitcnt vmcnt(0)"
                 : "=&v"(r) : "v"(p) : "memory");
    return r;
}

// Persistent LSTM: one launch runs all 2048 timesteps.
// grid = 32 batches x 8 slices, block = 512 threads, 1 block/CU.
//
// R2 (tagged words, VERIFIED 3903us): each h element is ONE u32
// (tag<<16 | f16); writers publish with relaxed AGENT atomics, readers
// poll the data words with agent loads. The tag IS the flag; a 32-bit
// store cannot tear; no fences needed.
// R5 post-mortem: sc0 (XCD-L2) polling is STRICTLY worse than MALL polling
// (remote agent stores invalidate, not update, the L2 line -> sc0 poll =
// stale hit or L2-miss-then-MALL). Reverted to the proven R2 protocol.
// R6 (this round):
//  (a) dwordx4 polls -- one lane validates 4 tagged words (2 LDS slots),
//      halving poll lanes (256->128/block) and MALL request rate; every
//      u32 remains self-validating so the protocol is unchanged.
//  (b) amdgpu_waves_per_eu(2,2): wgt[4][48]=192 u32/lane cannot fit in
//      the 128 arch VGPRs rocprof reported -> part of wgt sat in AGPRs
//      with v_accvgpr_read moves inside the dot loop. At our exact
//      occupancy (2 waves/SIMD) the budget is 256; tell the allocator to
//      use it.
//
// Race-freedom sketch (2-deep h parity buffer + gp parity):
//  - tag T lives in parity T&1; word tag T overwritten by T+2 only after
//    the owner slice finished step T+1, which required tag-(T+1) words from
//    ALL slices, which required every block's UPDATE(T), which is after
//    every block's barrier(T), which is after all polls for tag T passed.
//  - any wave's iteration-(t+2) write of gp[t&1] is program-ordered after
//    barrier(t+1), which requires wave 0's arrival, which follows
//    UPDATE(t)'s gp[t&1] reads.
__global__ __launch_bounds__(NTHR, 2)
__attribute__((amdgpu_waves_per_eu(2, 2)))
void lstm_persist(
    const float* __restrict__ x, const int* __restrict__ lens,
    const float* __restrict__ Wi, const float* __restrict__ Wh,
    const float* __restrict__ bias, float* __restrict__ out,
    uint32_t* __restrict__ hT)    // [2][BATCH][HDIM] u32 tagged f16
{
    // Block -> (batch, slice); keeps a batch's 8 blocks on one XCD under the
    // blockIdx%8 round-robin heuristic (perf only, not correctness).
    const int bid = blockIdx.x;
    const int xcd = bid & 7;
    const int t8  = bid >> 3;          // 0..31
    const int b   = xcd * 4 + (t8 & 3);
    const int s   = t8 >> 2;           // slice 0..7

    const int tid = threadIdx.x;
    const int w   = tid >> 6;          // wave 0..7 -> k-chunk [96w, 96w+96)
    const int l   = tid & 63;          // lane -> gate-cols {4l..4l+3}

    __shared__ __align__(16) uint32_t u_lds[NWAVE][KL2];  // per-wave chunk, f16x2
    __shared__ float gp[2][NWAVE][CPB];                   // parity-dbuf partials

    // ---- one-time: weight slice -> registers, packed f16x2 --------------
    // wgt[q][m] covers gate-col (4l+q), k = {96w+2m, 96w+2m+1};
    // k<256 indexes Wi rows, k>=256 indexes Wh rows (fused operand order).
    uint32_t wgt[4][KL2];
    #pragma unroll
    for (int q = 0; q < 4; ++q) {
        const int c    = 4 * l + q;                       // local gate-col
        const int gcol = (c >> 6) * HDIM + s * HCB + (c & 63);
        #pragma unroll
        for (int m = 0; m < KL2; ++m) {
            const int k0 = KL * w + 2 * m;
            const int k1 = k0 + 1;
            const float f0 = (k0 < DIN) ? Wi[(size_t)k0 * G4 + gcol]
                                        : Wh[(size_t)(k0 - DIN) * G4 + gcol];
            const float f1 = (k1 < DIN) ? Wi[(size_t)k1 * G4 + gcol]
                                        : Wh[(size_t)(k1 - DIN) * G4 + gcol];
            wgt[q][m] = pack_f16x2(f0, f1);
        }
    }

    // update-thread persistent state (wave 0, lane j owns h-col s*64+j)
    float c_st = 0.f, lc_st = 0.f, lh_st = 0.f;
    float b_i = 0.f, b_f = 0.f, b_g = 0.f, b_o = 0.f;
    if (tid < HCB) {
        const int col = s * HCB + tid;
        b_i = bias[col];
        b_f = bias[HDIM + col];
        b_g = bias[2 * HDIM + col];
        b_o = bias[3 * HDIM + col];
    }
    const int len_b = lens[b];

    const float* xb = x + (size_t)b * TLEN * DIN;
    float* ys = out + 2 * BATCH * HDIM;   // out = [lc | lh | ys]

    // staging roles:
    //  x lane: l<48, slot l, k0=96w+2l < 256 -> float2 load + pack.
    //  h lane: l<24, words [hk0-256, +4) -> one dwordx4 tagged poll filling
    //          slots {2l, 2l+1}. Boundary is clean: the x/h split 96w+4l=256
    //          falls on integer l (w=2 -> l=16), so no mixed quads exist.
    //          Wave-2 lanes 16..23 legitimately hold BOTH roles.
    const int  k0    = KL * w + 2 * l;           // x-slot first k
    const int  hk0   = KL * w + 4 * l;           // h-quad first k
    const bool is_x  = (l < KL2) && (k0 < DIN);
    const bool is_h4 = (l < KL2 / 2) && (hk0 >= DIN);

    // x prefetch one step ahead: keeps the HBM latency off the
    // publish->poll critical path.
    float2 xx_cur = make_float2(0.f, 0.f);
    if (is_x) xx_cur = *(const float2*)(xb + k0);           // t = 0

    for (int t = 0; t < TLEN; ++t) {
        // ---- stage own chunk ------------------------------------------
        if (is_x) {
            u_lds[w][l] = pack_f16x2(xx_cur.x, xx_cur.y);
            // issue next step's x load now; consumed next iteration
            if (t + 1 < TLEN)
                xx_cur = *(const float2*)(xb + (size_t)(t + 1) * DIN + k0);
        }
        if (is_h4) {
            // poll 4 tagged words with one agent dwordx4 load; tag==t means
            // h_t payload is valid (parity t&1 holds tag t). Each u32 is
            // self-validating, so inter-word tearing is harmless.
            const uint32_t* src =
                hT + (((size_t)(t & 1) * BATCH + b) * HDIM + (hk0 - DIN));
            const uint32_t tag = (uint32_t)t;
            u32x4 v;
            for (;;) {
                v = load_agent_u128(src);
                if ((v.x >> 16) == tag && (v.y >> 16) == tag &&
                    (v.z >> 16) == tag && (v.w >> 16) == tag) break;
            }
            // pack 4 f16 payloads -> 2 LDS slots (one ds_write_b64)
            uint2 pr;
            pr.x = (v.x & 0xFFFFu) | (v.y << 16);
            pr.y = (v.z & 0xFFFFu) | (v.w << 16);
            *(uint2*)&u_lds[w][2 * l] = pr;
        }

        // ---- dot phase: 4 gate-cols per lane, wave's 96-k chunk ---------
        float a0 = 0.f, a1 = 0.f, a2 = 0.f, a3 = 0.f;
        const uint4* uv = (const uint4*)&u_lds[w][0];
        #pragma unroll
        for (int m4 = 0; m4 < KL2 / 4; ++m4) {
            const uint4 uu = uv[m4];   // broadcast ds_read_b128
            a0 = dot2f(wgt[0][4 * m4 + 0], uu.x, a0);
            a0 = dot2f(wgt[0][4 * m4 + 1], uu.y, a0);
            a0 = dot2f(wgt[0][4 * m4 + 2], uu.z, a0);
            a0 = dot2f(wgt[0][4 * m4 + 3], uu.w, a0);
            a1 = dot2f(wgt[1][4 * m4 + 0], uu.x, a1);
            a1 = dot2f(wgt[1][4 * m4 + 1], uu.y, a1);
            a1 = dot2f(wgt[1][4 * m4 + 2], uu.z, a1);
            a1 = dot2f(wgt[1][4 * m4 + 3], uu.w, a1);
            a2 = dot2f(wgt[2][4 * m4 + 0], uu.x, a2);
            a2 = dot2f(wgt[2][4 * m4 + 1], uu.y, a2);
            a2 = dot2f(wgt[2][4 * m4 + 2], uu.z, a2);
            a2 = dot2f(wgt[2][4 * m4 + 3], uu.w, a2);
            a3 = dot2f(wgt[3][4 * m4 + 0], uu.x, a3);
            a3 = dot2f(wgt[3][4 * m4 + 1], uu.y, a3);
            a3 = dot2f(wgt[3][4 * m4 + 2], uu.z, a3);
            a3 = dot2f(wgt[3][4 * m4 + 3], uu.w, a3);
        }
        float4 av;
        av.x = a0; av.y = a1; av.z = a2; av.w = a3;
        *(float4*)&gp[t & 1][w][4 * l] = av;

        __syncthreads();   // the ONLY barrier per step

        // ---- update phase: wave 0 reduces 8 k-chunks, applies gates -----
        if (tid < HCB) {
            float si = b_i, sf = b_f, sg = b_g, so = b_o;
            #pragma unroll
            for (int ww = 0; ww < NWAVE; ++ww) {
                si += gp[t & 1][ww][tid];
                sf += gp[t & 1][ww][HCB + tid];
                sg += gp[t & 1][ww][2 * HCB + tid];
                so += gp[t & 1][ww][3 * HCB + tid];
            }
            const float ig = sigmoidf_(si);
            const float fg = sigmoidf_(sf);
            const float gg = tanhf_(sg);
            const float og = sigmoidf_(so);
            const float cn = fg * c_st + ig * gg;
            const float hn = og * tanhf_(cn);
            c_st = cn;
            if (t < len_b) { lc_st = cn; lh_st = hn; }
            // publish tagged h_{t+1} word to the other parity buffer
            // (relaxed agent store: write-through to the MALL coherence
            // point; 32-bit store cannot tear; the tag IS the flag)
            const _Float16 hf = (_Float16)hn;
            const uint32_t word = ((uint32_t)(t + 1) << 16) |
                                  (uint32_t)__builtin_bit_cast(uint16_t, hf);
            __hip_atomic_store(
                &hT[((size_t)((t + 1) & 1) * BATCH + b) * HDIM + s * HCB + tid],
                word, __ATOMIC_RELAXED, __HIP_MEMORY_SCOPE_AGENT);
            // ys output (fp32, unmasked like the reference scan)
            ys[((size_t)b * TLEN + t) * HDIM + s * HCB + tid] = hn;
        }
        // no second barrier: gp parity double-buffer covers the one-step
        // overlap, and the tagged-word dependency chain covers step t+2.
    }

    // latched carry outputs
    if (tid < HCB) {
        out[(size_t)b * HDIM + s * HCB + tid] = lc_st;
        out[BATCH * HDIM + (size_t)b * HDIM + s * HCB + tid] = lh_st;
    }
}

extern "C" void kernel_launch(void* const* d_in, const int* in_sizes, int n_in,
                              void* d_out, int out_size, void* d_ws, size_t ws_size,
                              hipStream_t stream)
{
    const float* x    = (const float*)d_in[0];   // [32,2048,256] f32
    const int*   lens = (const int*)d_in[1];     // [32] i32
    const float* Wi   = (const float*)d_in[2];   // [256,2048] f32
    const float* Wh   = (const float*)d_in[3];   // [512,2048] f32
    const float* bias = (const float*)d_in[4];   // [2048] f32
    float* out = (float*)d_out;                  // [lc(16384) | lh(16384) | ys]

    uint32_t* hT = (uint32_t*)d_ws;              // [2][32][512] tagged u32
    // Zero BOTH parities: parity 0 = (tag=0, h=0) satisfies t=0 polls
    // immediately (h_0 = 0); parity 1 = tag 0, which matches no polled tag
    // (polled tags in parity 1 are odd >= 1), so readers spin until written.
    const size_t init_bytes = (size_t)2 * BATCH * HDIM * sizeof(uint32_t);
    hipMemsetAsync(d_ws, 0, init_bytes, stream);

    hipLaunchKernelGGL(lstm_persist, dim3(NBLK), dim3(NTHR), 0, stream,
                       x, lens, Wi, Wh, bias, out, hT);
}